// Round 6
// baseline (457.979 us; speedup 1.0000x reference)
//
#include <hip/hip_runtime.h>
#include <stdint.h>

#define BATCH 256
#define DBLK  16          // d
#define OB    128         // hidden nodes per diagonal block (M)
#define NN    2048        // M*D
#define NCONV 1024        // convert blocks in k_prep

using bf16x8  = __attribute__((ext_vector_type(8))) __bf16;
using f32x4   = __attribute__((ext_vector_type(4))) float;
using ushort8 = __attribute__((ext_vector_type(8))) unsigned short;

__device__ __forceinline__ unsigned short f2bf(float f) {
    union { float f; uint32_t u; } v; v.f = f;
    uint32_t u = v.u;
    uint32_t r = (u + 0x7fffu + ((u >> 16) & 1u)) >> 16;   // RNE
    return (unsigned short)r;
}

__device__ __forceinline__ float bf2f(unsigned short h) {
    union { uint32_t u; float f; } v; v.u = ((uint32_t)h) << 16;
    return v.f;
}

// fused fast tanh + log|tanh'|: one __expf + one __logf.
// tanh(x) = sign(x)*(1 - 2e/(1+e)), e = exp(-2|x|)
// log|tanh'(x)| = 2*(ln2 - |x| - log(1+e))
__device__ __forceinline__ void act_tanh_lga(float x, float& th, float& lga) {
    float ax = fabsf(x);
    float e  = __expf(-2.f * ax);
    float p  = 1.f + e;
    float t  = 1.f - __fdividef(2.f * e, p);
    th  = (x < 0.f) ? -t : t;
    lga = 2.f * (0.69314718055994531f - ax - __logf(p));
}

// ---- layer0 for one batch row, threads t=0..255: thread t -> outputs j=t*8..t*8+7
__device__ __forceinline__ void l0_block(const float* __restrict__ xs,   // 16 floats
                                         const float* __restrict__ W0,
                                         const float* __restrict__ b0,
                                         unsigned short* __restrict__ h0,
                                         unsigned short* __restrict__ e0,
                                         float* __restrict__ mmax,
                                         int b, int t) {
    const int j0 = t * 8;
    const int dd = t >> 4;
    float g[8];
    unsigned short hv[8];
    float lm = -1e30f;
    #pragma unroll
    for (int q = 0; q < 8; ++q) {
        const int j = j0 + q;
        const float* wrow = W0 + (size_t)j * DBLK;
        float s = b0[j];
        #pragma unroll
        for (int c = 0; c < DBLK; c += 4) {
            float4 wv = *(const float4*)(wrow + c);
            s += wv.x * xs[c] + wv.y * xs[c + 1] + wv.z * xs[c + 2] + wv.w * xs[c + 3];
        }
        float th, lga;
        act_tanh_lga(s, th, lga);
        hv[q] = f2bf(th);
        g[q]  = __logf(wrow[dd]) + lga;
        lm = fmaxf(lm, g[q]);
    }
    #pragma unroll
    for (int off = 1; off < 16; off <<= 1) lm = fmaxf(lm, __shfl_xor(lm, off));
    ushort8 hh, ee;
    #pragma unroll
    for (int q = 0; q < 8; ++q) {
        hh[q] = hv[q];
        ee[q] = f2bf(__expf(g[q] - lm));
    }
    *(ushort8*)(h0 + (size_t)b * NN + j0) = hh;
    *(ushort8*)(e0 + (size_t)b * NN + j0) = ee;
    if ((t & 15) == 0) mmax[b * DBLK + dd] = lm;
}

__device__ __forceinline__ void conv_row(const float* __restrict__ src,
                                         unsigned short* __restrict__ out,
                                         int row, int t) {
    const int kend = ((row >> 7) + 1) * OB;     // triangular extent, mult of 128
    const int k = t * 8;
    if (k < kend) {
        float4 v0 = *(const float4*)(src + k);
        float4 v1 = *(const float4*)(src + k + 4);
        ushort8 u;
        u[0] = f2bf(v0.x); u[1] = f2bf(v0.y); u[2] = f2bf(v0.z); u[3] = f2bf(v0.w);
        u[4] = f2bf(v1.x); u[5] = f2bf(v1.y); u[6] = f2bf(v1.z); u[7] = f2bf(v1.w);
        *(ushort8*)(out + k) = u;
    }
}

// ---- P1: blocks [0,NCONV): convert flow0 W1 rows {b, 2047-b};
//          blocks [NCONV,NCONV+256): layer0 of flow 0 + zero the tickets
__global__ void k_prep(const float* __restrict__ W1a,
                       unsigned short* __restrict__ W1bf,
                       const float* __restrict__ inp,
                       const float* __restrict__ W00,
                       const float* __restrict__ b00,
                       unsigned short* __restrict__ h0,
                       unsigned short* __restrict__ e0,
                       float* __restrict__ mmax,
                       int* __restrict__ cnt) {
    const int gb = blockIdx.x;
    const int t  = threadIdx.x;
    if (gb < NCONV) {
        const int r0 = gb;
        const int r1 = NN - 1 - gb;
        conv_row(W1a + (size_t)r0 * NN, W1bf + (size_t)r0 * NN, r0, t);
        conv_row(W1a + (size_t)r1 * NN, W1bf + (size_t)r1 * NN, r1, t);
    } else {
        const int b = gb - NCONV;
        if (b == 0 && t < 32) cnt[t] = 0;
        l0_block(inp + (size_t)b * DBLK, W00, b00, h0, e0, mmax, b, t);
    }
}

// ---- mega kernel: layer1 tile + per-batch-tile fused epilogue (ticketed).
// grid (dd=16, bt=16, z): z<4 = layer1 ct; (FLOW==0) z>=4 = convert flow1 W1.
// Last block of tile bt does: out2 dots + lse  -> x-row, log-det;
//   FLOW==0: + layer0 of flow1 for those rows; FLOW==1: writes d_out.
template<int FLOW>
__global__ void __launch_bounds__(512, 8)
k_flow(const unsigned short* __restrict__ h0,
       const unsigned short* __restrict__ W1b,
       const float* __restrict__ b1v,
       const unsigned short* __restrict__ e0,
       const float* __restrict__ mmax,
       unsigned short* __restrict__ h1,
       float* __restrict__ g1,
       const float* __restrict__ W2,
       int* __restrict__ cnt,
       const float* __restrict__ W1next,        // FLOW==0: flow1 W1 (fp32)
       unsigned short* __restrict__ W1bfnext,   // FLOW==0: flow1 W1 (bf16 out)
       const float* __restrict__ W0n,           // FLOW==0: flow1 W0
       const float* __restrict__ b0n,
       unsigned short* __restrict__ h0n,
       unsigned short* __restrict__ e0n,
       float* __restrict__ mmaxn,
       float* __restrict__ ld0,                 // FLOW==0 out / FLOW==1 in
       float* __restrict__ out_final,
       float* __restrict__ ld_final) {
    const int tid = threadIdx.x;

    if (FLOW == 0 && blockIdx.z >= 4) {
        // convert flow1 W1: unit c -> rows {c, 2047-c}, half-block each
        const int c   = blockIdx.x * 64 + blockIdx.y * 4 + ((int)blockIdx.z - 4);
        const int row = (tid < 256) ? c : (NN - 1 - c);
        conv_row(W1next + (size_t)row * NN, W1bfnext + (size_t)row * NN, row, tid & 255);
        return;
    }

    const int dd    = blockIdx.x;
    const int bt    = blockIdx.y;
    const int ct    = blockIdx.z;
    const int w     = tid >> 6;      // 0..7
    const int lane  = tid & 63;
    const int brow0 = bt * 16;
    const int arow  = brow0 + (lane & 15);
    const int koff  = (lane >> 4) * 8;
    const int ncol  = lane & 15;
    const int col0  = dd * OB + ct * 32;

    f32x4 acc[2], acc2[2];
    #pragma unroll
    for (int nt = 0; nt < 2; ++nt) {
        acc[nt]  = (f32x4){0.f, 0.f, 0.f, 0.f};
        acc2[nt] = (f32x4){0.f, 0.f, 0.f, 0.f};
    }

    const unsigned short* Ab = h0 + (size_t)arow * NN + koff;
    const unsigned short* Bb[2];
    #pragma unroll
    for (int nt = 0; nt < 2; ++nt)
        Bb[nt] = W1b + (size_t)(col0 + nt * 16 + ncol) * NN + koff;

    // GEMM: wave w takes chunks c = w, w+8, ... of the (dd+1)*4 chunks
    const int nch = (dd + 1) * 4;
    #pragma unroll 2
    for (int c = w; c < nch; c += 8) {
        const int k = c * 32;
        bf16x8 a   = *(const bf16x8*)(Ab + k);
        bf16x8 b0v = *(const bf16x8*)(Bb[0] + k);
        bf16x8 b1w = *(const bf16x8*)(Bb[1] + k);
        acc[0] = __builtin_amdgcn_mfma_f32_16x16x32_bf16(a, b0v, acc[0], 0, 0, 0);
        acc[1] = __builtin_amdgcn_mfma_f32_16x16x32_bf16(a, b1w, acc[1], 0, 0, 0);
    }

    // grad matvec over the 128-wide diagonal block: waves 0..3, one chunk each
    if (w < 4) {
        const int k2 = dd * OB + w * 32;
        bf16x8 a = *(const bf16x8*)(e0 + (size_t)arow * NN + koff + k2);
        acc2[0] = __builtin_amdgcn_mfma_f32_16x16x32_bf16(a, *(const bf16x8*)(Bb[0] + k2), acc2[0], 0, 0, 0);
        acc2[1] = __builtin_amdgcn_mfma_f32_16x16x32_bf16(a, *(const bf16x8*)(Bb[1] + k2), acc2[1], 0, 0, 0);
    }

    __shared__ float ls1[8][2][64][4];
    __shared__ float ls2[4][2][64][4];
    #pragma unroll
    for (int nt = 0; nt < 2; ++nt)
        *(f32x4*)&ls1[w][nt][lane][0] = acc[nt];
    if (w < 4) {
        #pragma unroll
        for (int nt = 0; nt < 2; ++nt)
            *(f32x4*)&ls2[w][nt][lane][0] = acc2[nt];
    }
    __syncthreads();

    {
        const int o  = tid;                    // 0..511 output index in tile
        const int rr = o >> 5;                 // 0..15 row in tile
        const int cc = o & 31;                 // 0..31 col in tile
        const int nt = cc >> 4;
        const int r  = rr & 3;
        const int ls = (rr >> 2) * 16 + (cc & 15);
        float S = 0.f, S2 = 0.f;
        #pragma unroll
        for (int ww = 0; ww < 8; ++ww) S += ls1[ww][nt][ls][r];
        #pragma unroll
        for (int ww = 0; ww < 4; ++ww) S2 += ls2[ww][nt][ls][r];
        const int j    = col0 + cc;
        const int brow = brow0 + rr;
        const float pre = S + b1v[j];
        float th, lga;
        act_tanh_lga(pre, th, lga);
        h1[(size_t)brow * NN + j] = f2bf(th);
        g1[(size_t)brow * NN + j] = __logf(S2) + mmax[brow * DBLK + dd] + lga;
    }

    // ---------------- ticket: last of the 64 blocks of tile bt runs the epilogue
    __shared__ int is_last;
    __syncthreads();                 // all tile stores complete (to this XCD's L2)
    if (tid == 0) {
        __threadfence();             // release: write back to device-visible
        int old = __hip_atomic_fetch_add(&cnt[bt], 1, __ATOMIC_ACQ_REL,
                                         __HIP_MEMORY_SCOPE_AGENT);
        is_last = (old == 63);
    }
    __syncthreads();
    if (!is_last) return;
    __threadfence();                 // acquire: invalidate before reading peers' data

    // ---------------- fused final for the 16 rows of this tile ----------------
    __shared__ float sxs[16][16];    // [rr][dd] : x-row after final linear layer
    __shared__ float gfs[16][16];    // [rr][dd] : final lse per (row, dd)
    const int slot = lane >> 4;      // 0..3
    const int sl   = lane & 15;
    #pragma unroll
    for (int round = 0; round < 8; ++round) {
        const int p   = round * 32 + w * 4 + slot;   // 0..255 = (rr, dd2)
        const int rr  = p >> 4;
        const int dd2 = p & 15;
        const int r   = brow0 + rr;
        const unsigned short* hrow = h1 + (size_t)r * NN;
        const float* w2r = W2 + (size_t)dd2 * NN;
        const int kend = (dd2 + 1) * OB;
        float s = 0.f;
        for (int k = sl * 4; k < kend; k += 64) {
            ushort4 hv4 = *(const ushort4*)(hrow + k);
            float4  wv  = *(const float4*)(w2r + k);
            s += bf2f(hv4.x) * wv.x + bf2f(hv4.y) * wv.y
               + bf2f(hv4.z) * wv.z + bf2f(hv4.w) * wv.w;
        }
        #pragma unroll
        for (int off = 8; off > 0; off >>= 1) s += __shfl_xor(s, off);
        // lse over the 128-wide diagonal block
        const float* grow = g1 + (size_t)r * NN + dd2 * OB;
        float v[8];
        #pragma unroll
        for (int j2 = 0; j2 < 8; ++j2) v[j2] = grow[sl + j2 * 16];
        float mx = v[0];
        #pragma unroll
        for (int j2 = 1; j2 < 8; ++j2) mx = fmaxf(mx, v[j2]);
        #pragma unroll
        for (int off = 8; off > 0; off >>= 1) mx = fmaxf(mx, __shfl_xor(mx, off));
        float e = 0.f;
        #pragma unroll
        for (int j2 = 0; j2 < 8; ++j2)
            e += __expf(v[j2] - mx) * w2r[dd2 * OB + sl + j2 * 16];
        #pragma unroll
        for (int off = 8; off > 0; off >>= 1) e += __shfl_xor(e, off);
        if (sl == 0) {
            sxs[rr][dd2] = s;
            gfs[rr][dd2] = __logf(e) + mx;
        }
    }
    __syncthreads();

    if (tid < 16) {
        float ldv = 0.f;
        #pragma unroll
        for (int q = 0; q < DBLK; ++q) ldv += gfs[tid][q];
        if (FLOW == 0) ld0[brow0 + tid] = ldv;
        else           ld_final[brow0 + tid] = ldv + ld0[brow0 + tid];
    }
    if (FLOW == 0) {
        // layer0 of flow 1 for these 16 rows (2 rows per pass, 8 passes)
        #pragma unroll
        for (int half = 0; half < 8; ++half) {
            const int rr = half * 2 + (tid >> 8);
            l0_block(&sxs[rr][0], W0n, b0n, h0n, e0n, mmaxn, brow0 + rr, tid & 255);
        }
    } else {
        if (tid < 256)
            out_final[(size_t)(brow0 + (tid >> 4)) * DBLK + (tid & 15)] = sxs[tid >> 4][tid & 15];
    }
}

extern "C" void kernel_launch(void* const* d_in, const int* in_sizes, int n_in,
                              void* d_out, int out_size, void* d_ws, size_t ws_size,
                              hipStream_t stream) {
    const float* inp   = (const float*)d_in[0];
    const float* W0[2] = {(const float*)d_in[1], (const float*)d_in[6]};
    const float* W1[2] = {(const float*)d_in[2], (const float*)d_in[7]};
    const float* W2[2] = {(const float*)d_in[3], (const float*)d_in[8]};
    const float* b0[2] = {(const float*)d_in[4], (const float*)d_in[9]};
    const float* b1[2] = {(const float*)d_in[5], (const float*)d_in[10]};

    char* w = (char*)d_ws;
    size_t off = 0;
    unsigned short* W1bf = (unsigned short*)(w + off); off += (size_t)2 * NN * NN * 2; // 16 MB
    unsigned short* h0a  = (unsigned short*)(w + off); off += (size_t)BATCH * NN * 2;
    unsigned short* e0a  = (unsigned short*)(w + off); off += (size_t)BATCH * NN * 2;
    unsigned short* h0c  = (unsigned short*)(w + off); off += (size_t)BATCH * NN * 2;
    unsigned short* e0c  = (unsigned short*)(w + off); off += (size_t)BATCH * NN * 2;
    float* mmax0 = (float*)(w + off); off += (size_t)BATCH * DBLK * 4;
    float* mmax1 = (float*)(w + off); off += (size_t)BATCH * DBLK * 4;
    unsigned short* h1 = (unsigned short*)(w + off); off += (size_t)BATCH * NN * 2;
    float* g1   = (float*)(w + off); off += (size_t)BATCH * NN * 4;
    float* ld0  = (float*)(w + off); off += (size_t)BATCH * 4;
    int*   cnt  = (int*)(w + off);   off += 32 * 4;

    float* out_final = (float*)d_out;                 // (256,16)
    float* ld_final  = (float*)d_out + BATCH * DBLK;  // (256,)

    // P1: convert flow0 W1 + layer0 flow 0 + zero tickets
    k_prep<<<dim3(NCONV + BATCH), dim3(256), 0, stream>>>(
        W1[0], W1bf, inp, W0[0], b0[0], h0a, e0a, mmax0, cnt);

    // P2: flow 0 (layer1 + fused final0 + layer0 of flow1) ∥ convert flow1 W1
    k_flow<0><<<dim3(DBLK, 16, 8), dim3(512), 0, stream>>>(
        h0a, W1bf, b1[0], e0a, mmax0, h1, g1, W2[0], cnt,
        W1[1], W1bf + (size_t)NN * NN,
        W0[1], b0[1], h0c, e0c, mmax1,
        ld0, nullptr, nullptr);

    // P3: flow 1 (layer1 + fused final1 -> d_out)
    k_flow<1><<<dim3(DBLK, 16, 4), dim3(512), 0, stream>>>(
        h0c, W1bf + (size_t)NN * NN, b1[1], e0c, mmax1, h1, g1, W2[1], cnt + 16,
        nullptr, nullptr, nullptr, nullptr, nullptr, nullptr, nullptr,
        ld0, out_final, ld_final);
}

// Round 7
// 88.479 us; speedup vs baseline: 5.1761x; 5.1761x over previous
//
#include <hip/hip_runtime.h>
#include <stdint.h>

#define BATCH 256
#define DBLK  16          // d
#define OB    128         // hidden nodes per diagonal block (M)
#define NN    2048        // M*D

using bf16x8  = __attribute__((ext_vector_type(8))) __bf16;
using f32x4   = __attribute__((ext_vector_type(4))) float;
using ushort8 = __attribute__((ext_vector_type(8))) unsigned short;

__device__ __forceinline__ unsigned short f2bf(float f) {
    union { float f; uint32_t u; } v; v.f = f;
    uint32_t u = v.u;
    uint32_t r = (u + 0x7fffu + ((u >> 16) & 1u)) >> 16;   // RNE
    return (unsigned short)r;
}

__device__ __forceinline__ float bf2f(unsigned short h) {
    union { uint32_t u; float f; } v; v.u = ((uint32_t)h) << 16;
    return v.f;
}

// fused fast tanh + log|tanh'|: one __expf + one __logf.
__device__ __forceinline__ void act_tanh_lga(float x, float& th, float& lga) {
    float ax = fabsf(x);
    float e  = __expf(-2.f * ax);
    float p  = 1.f + e;
    float t  = 1.f - __fdividef(2.f * e, p);
    th  = (x < 0.f) ? -t : t;
    lga = 2.f * (0.69314718055994531f - ax - __logf(p));
}

__device__ __forceinline__ ushort8 pack_bf8(float4 a, float4 b) {
    ushort8 u;
    u[0] = f2bf(a.x); u[1] = f2bf(a.y); u[2] = f2bf(a.z); u[3] = f2bf(a.w);
    u[4] = f2bf(b.x); u[5] = f2bf(b.y); u[6] = f2bf(b.z); u[7] = f2bf(b.w);
    return u;
}

// ---- layer0 for one batch row, 256 threads: thread t -> outputs j=t*8..t*8+7
__device__ __forceinline__ void l0_block(const float* __restrict__ xs,
                                         const float* __restrict__ W0,
                                         const float* __restrict__ b0,
                                         unsigned short* __restrict__ h0,
                                         unsigned short* __restrict__ e0,
                                         float* __restrict__ mmax,
                                         int b, int t) {
    const int j0 = t * 8;
    const int dd = t >> 4;
    float g[8];
    unsigned short hv[8];
    float lm = -1e30f;
    #pragma unroll
    for (int q = 0; q < 8; ++q) {
        const int j = j0 + q;
        const float* wrow = W0 + (size_t)j * DBLK;
        float s = b0[j];
        #pragma unroll
        for (int c = 0; c < DBLK; c += 4) {
            float4 wv = *(const float4*)(wrow + c);
            s += wv.x * xs[c] + wv.y * xs[c + 1] + wv.z * xs[c + 2] + wv.w * xs[c + 3];
        }
        float th, lga;
        act_tanh_lga(s, th, lga);
        hv[q] = f2bf(th);
        g[q]  = __logf(wrow[dd]) + lga;
        lm = fmaxf(lm, g[q]);
    }
    #pragma unroll
    for (int off = 1; off < 16; off <<= 1) lm = fmaxf(lm, __shfl_xor(lm, off));
    ushort8 hh, ee;
    #pragma unroll
    for (int q = 0; q < 8; ++q) {
        hh[q] = hv[q];
        ee[q] = f2bf(__expf(g[q] - lm));
    }
    *(ushort8*)(h0 + (size_t)b * NN + j0) = hh;
    *(ushort8*)(e0 + (size_t)b * NN + j0) = ee;
    if ((t & 15) == 0) mmax[b * DBLK + dd] = lm;
}

// ---- layer0, 512-thread variant: thread t -> outputs j = (t>>5)*128 + (t&31)*4 ..+3
__device__ __forceinline__ void l0_block512(const float* __restrict__ xs,
                                            const float* __restrict__ W0,
                                            const float* __restrict__ b0,
                                            unsigned short* __restrict__ h0,
                                            unsigned short* __restrict__ e0,
                                            float* __restrict__ mmax,
                                            int b, int t) {
    const int dd = t >> 5;
    const int j0 = dd * OB + (t & 31) * 4;
    float g[4];
    unsigned short hv[4];
    float lm = -1e30f;
    #pragma unroll
    for (int q = 0; q < 4; ++q) {
        const int j = j0 + q;
        const float* wrow = W0 + (size_t)j * DBLK;
        float s = b0[j];
        #pragma unroll
        for (int c = 0; c < DBLK; c += 4) {
            float4 wv = *(const float4*)(wrow + c);
            s += wv.x * xs[c] + wv.y * xs[c + 1] + wv.z * xs[c + 2] + wv.w * xs[c + 3];
        }
        float th, lga;
        act_tanh_lga(s, th, lga);
        hv[q] = f2bf(th);
        g[q]  = __logf(wrow[dd]) + lga;
        lm = fmaxf(lm, g[q]);
    }
    #pragma unroll
    for (int off = 1; off < 32; off <<= 1) lm = fmaxf(lm, __shfl_xor(lm, off));
    ushort4 hh, ee;
    #pragma unroll
    for (int q = 0; q < 4; ++q) {
        ((unsigned short*)&hh)[q] = hv[q];
        ((unsigned short*)&ee)[q] = f2bf(__expf(g[q] - lm));
    }
    *(ushort4*)(h0 + (size_t)b * NN + j0) = hh;
    *(ushort4*)(e0 + (size_t)b * NN + j0) = ee;
    if ((t & 31) == 0) mmax[b * DBLK + dd] = lm;
}

// ---- P1: blocks [0,1024): convert flow0 W1 pair {p, 2047-p} — all loads
//          hoisted to registers before any store (latency pipelining);
//          blocks [1024,1280): layer0 of flow 0
__global__ void k_prep(const float* __restrict__ W1a,
                       unsigned short* __restrict__ W1bf,
                       const float* __restrict__ inp,
                       const float* __restrict__ W00,
                       const float* __restrict__ b00,
                       unsigned short* __restrict__ h0,
                       unsigned short* __restrict__ e0,
                       float* __restrict__ mmax) {
    const int gb = blockIdx.x;
    const int t  = threadIdx.x;
    if (gb < 1024) {
        const int p     = gb;
        const int kend0 = ((p >> 7) + 1) * OB;
        const float* s0 = W1a + (size_t)p * NN;
        const float* s1 = W1a + (size_t)(NN - 1 - p) * NN;
        unsigned short* d0 = W1bf + (size_t)p * NN;
        unsigned short* d1 = W1bf + (size_t)(NN - 1 - p) * NN;
        // virtual 2176-float extent = row p (kend0) ++ row 2047-p (2176-kend0)
        float4 va[2][2];
        unsigned short* dp[2];
        bool act[2];
        #pragma unroll
        for (int i = 0; i < 2; ++i) {
            const int c  = t + i * 256;
            act[i] = (c < 272);
            if (act[i]) {
                const int off = c * 8;
                const float* sp;
                if (off < kend0) { sp = s0 + off;           dp[i] = d0 + off; }
                else             { sp = s1 + (off - kend0); dp[i] = d1 + (off - kend0); }
                va[i][0] = *(const float4*)(sp);
                va[i][1] = *(const float4*)(sp + 4);
            }
        }
        #pragma unroll
        for (int i = 0; i < 2; ++i)
            if (act[i]) *(ushort8*)dp[i] = pack_bf8(va[i][0], va[i][1]);
    } else {
        const int b = gb - 1024;
        l0_block(inp + (size_t)b * DBLK, W00, b00, h0, e0, mmax, b, t);
    }
}

// ---- layer1. grid (dd=16, bt=16, z), 512 thr (8 waves).
// z<4: tile = 16 batch rows x 32 cols, waves take interleaved 32-wide K-chunks.
// CONV && z==4: convert flow1 W1 (4 row-pairs per block, loads hoisted).
template<bool CONV>
__global__ void __launch_bounds__(512, 4)
k_l1(const unsigned short* __restrict__ h0,
     const unsigned short* __restrict__ W1b,
     const float* __restrict__ b1v,
     const unsigned short* __restrict__ e0,
     const float* __restrict__ mmax,
     unsigned short* __restrict__ h1,
     float* __restrict__ g1,
     const float* __restrict__ W1next,
     unsigned short* __restrict__ W1bfn) {
    const int tid = threadIdx.x;

    if (CONV && blockIdx.z == 4) {
        const int cid = (int)blockIdx.x * 16 + (int)blockIdx.y;   // 0..255
        // 4 pairs per block -> virtual 1088 chunks of 8 floats
        float4 va[3][2];
        unsigned short* dp[3];
        bool act[3];
        #pragma unroll
        for (int i = 0; i < 3; ++i) {
            const int c = tid + i * 512;
            act[i] = (c < 1088);
            if (act[i]) {
                const int pi  = c / 272;
                const int rem = c - pi * 272;
                const int p   = cid * 4 + pi;
                const int kend0 = ((p >> 7) + 1) * OB;
                const int off = rem * 8;
                const int row = (off < kend0) ? p : (NN - 1 - p);
                const int k   = (off < kend0) ? off : (off - kend0);
                const float* sp = W1next + (size_t)row * NN + k;
                dp[i] = W1bfn + (size_t)row * NN + k;
                va[i][0] = *(const float4*)(sp);
                va[i][1] = *(const float4*)(sp + 4);
            }
        }
        #pragma unroll
        for (int i = 0; i < 3; ++i)
            if (act[i]) *(ushort8*)dp[i] = pack_bf8(va[i][0], va[i][1]);
        return;
    }

    const int dd    = blockIdx.x;
    const int bt    = blockIdx.y;
    const int ct    = blockIdx.z;
    const int w     = tid >> 6;      // 0..7
    const int lane  = tid & 63;
    const int brow0 = bt * 16;
    const int arow  = brow0 + (lane & 15);
    const int koff  = (lane >> 4) * 8;
    const int ncol  = lane & 15;
    const int col0  = dd * OB + ct * 32;

    f32x4 acc[2], acc2[2];
    #pragma unroll
    for (int nt = 0; nt < 2; ++nt) {
        acc[nt]  = (f32x4){0.f, 0.f, 0.f, 0.f};
        acc2[nt] = (f32x4){0.f, 0.f, 0.f, 0.f};
    }

    const unsigned short* Ab = h0 + (size_t)arow * NN + koff;
    const unsigned short* Bb[2];
    #pragma unroll
    for (int nt = 0; nt < 2; ++nt)
        Bb[nt] = W1b + (size_t)(col0 + nt * 16 + ncol) * NN + koff;

    // GEMM: wave w takes chunks c = w, w+8, ... of the (dd+1)*4 chunks
    const int nch = (dd + 1) * 4;
    #pragma unroll 4
    for (int c = w; c < nch; c += 8) {
        const int k = c * 32;
        bf16x8 a   = *(const bf16x8*)(Ab + k);
        bf16x8 b0v = *(const bf16x8*)(Bb[0] + k);
        bf16x8 b1w = *(const bf16x8*)(Bb[1] + k);
        acc[0] = __builtin_amdgcn_mfma_f32_16x16x32_bf16(a, b0v, acc[0], 0, 0, 0);
        acc[1] = __builtin_amdgcn_mfma_f32_16x16x32_bf16(a, b1w, acc[1], 0, 0, 0);
    }

    // grad matvec over the 128-wide diagonal block: waves 0..3, one chunk each
    if (w < 4) {
        const int k2 = dd * OB + w * 32;
        bf16x8 a = *(const bf16x8*)(e0 + (size_t)arow * NN + koff + k2);
        acc2[0] = __builtin_amdgcn_mfma_f32_16x16x32_bf16(a, *(const bf16x8*)(Bb[0] + k2), acc2[0], 0, 0, 0);
        acc2[1] = __builtin_amdgcn_mfma_f32_16x16x32_bf16(a, *(const bf16x8*)(Bb[1] + k2), acc2[1], 0, 0, 0);
    }

    __shared__ float ls1[8][2][64][4];
    __shared__ float ls2[4][2][64][4];
    #pragma unroll
    for (int nt = 0; nt < 2; ++nt)
        *(f32x4*)&ls1[w][nt][lane][0] = acc[nt];
    if (w < 4) {
        #pragma unroll
        for (int nt = 0; nt < 2; ++nt)
            *(f32x4*)&ls2[w][nt][lane][0] = acc2[nt];
    }
    __syncthreads();

    {
        const int o  = tid;                    // 0..511 output index in tile
        const int rr = o >> 5;                 // 0..15 row in tile
        const int cc = o & 31;                 // 0..31 col in tile
        const int nt = cc >> 4;
        const int r  = rr & 3;
        const int ls = (rr >> 2) * 16 + (cc & 15);
        float S = 0.f, S2 = 0.f;
        #pragma unroll
        for (int ww = 0; ww < 8; ++ww) S += ls1[ww][nt][ls][r];
        #pragma unroll
        for (int ww = 0; ww < 4; ++ww) S2 += ls2[ww][nt][ls][r];
        const int j    = col0 + cc;
        const int brow = brow0 + rr;
        const float pre = S + b1v[j];
        float th, lga;
        act_tanh_lga(pre, th, lga);
        h1[(size_t)brow * NN + j] = f2bf(th);
        g1[(size_t)brow * NN + j] = __logf(S2) + mmax[brow * DBLK + dd] + lga;
    }
}

// ---- final-layer compute for one batch row, 512 threads: wave w -> dd = w, w+8.
__device__ __forceinline__ float final_compute(const unsigned short* __restrict__ h1,
                                               const float* __restrict__ g1,
                                               const float* __restrict__ W2,
                                               int b, int t,
                                               float* sh, float* gf, float* sx) {
    const int wave = t >> 6;
    const int lane = t & 63;
    {
        const int k = t * 4;
        ushort4 hv = *(const ushort4*)(h1 + (size_t)b * NN + k);
        float4 f0;
        f0.x = bf2f(hv.x); f0.y = bf2f(hv.y); f0.z = bf2f(hv.z); f0.w = bf2f(hv.w);
        *(float4*)(sh + k) = f0;
    }
    __syncthreads();

    #pragma unroll
    for (int q = 0; q < 2; ++q) {
        const int dd = wave + q * 8;           // balanced: (w+1)+(w+9) const
        const float* w2r = W2 + (size_t)dd * NN;
        const int kend = (dd + 1) * OB;
        float s = 0.f;
        for (int k = lane * 4; k < kend; k += 64 * 4) {
            float4 hv = *(const float4*)(sh + k);
            float4 wv = *(const float4*)(w2r + k);
            s += hv.x * wv.x + hv.y * wv.y + hv.z * wv.z + hv.w * wv.w;
        }
        #pragma unroll
        for (int off = 32; off > 0; off >>= 1) s += __shfl_xor(s, off);
        float v0 = g1[(size_t)b * NN + dd * OB + lane];
        float v1 = g1[(size_t)b * NN + dd * OB + 64 + lane];
        float m = fmaxf(v0, v1);
        #pragma unroll
        for (int off = 32; off > 0; off >>= 1) m = fmaxf(m, __shfl_xor(m, off));
        float e = __expf(v0 - m) * w2r[dd * OB + lane]
                + __expf(v1 - m) * w2r[dd * OB + 64 + lane];
        #pragma unroll
        for (int off = 32; off > 0; off >>= 1) e += __shfl_xor(e, off);
        if (lane == 0) {
            sx[dd] = s;
            gf[dd] = __logf(e) + m;
        }
    }
    __syncthreads();
    float ld = 0.f;
    #pragma unroll
    for (int dd = 0; dd < DBLK; ++dd) ld += gf[dd];
    return ld;
}

// ---- P3: final of flow 0 + layer0 of flow 1 (block b = batch row b)
__global__ void __launch_bounds__(512)
k_fin0(const unsigned short* __restrict__ h1,
       const float* __restrict__ g1,
       const float* __restrict__ W2,   // flow 0
       const float* __restrict__ W0n,  // flow 1
       const float* __restrict__ b0n,  // flow 1
       unsigned short* __restrict__ h0,
       unsigned short* __restrict__ e0,
       float* __restrict__ mmax,
       float* __restrict__ ld0) {
    __shared__ float sh[NN];
    __shared__ float gf[DBLK];
    __shared__ float sx[DBLK];
    const int b = blockIdx.x;
    const int t = threadIdx.x;
    float ld = final_compute(h1, g1, W2, b, t, sh, gf, sx);
    if (t == 0) ld0[b] = ld;
    l0_block512(sx, W0n, b0n, h0, e0, mmax, b, t);
}

// ---- P5: final of flow 1 -> d_out
__global__ void __launch_bounds__(512)
k_fin1(const unsigned short* __restrict__ h1,
       const float* __restrict__ g1,
       const float* __restrict__ W2,   // flow 1
       const float* __restrict__ ld0,
       float* __restrict__ out_final,
       float* __restrict__ ld_final) {
    __shared__ float sh[NN];
    __shared__ float gf[DBLK];
    __shared__ float sx[DBLK];
    const int b = blockIdx.x;
    const int t = threadIdx.x;
    float ld = final_compute(h1, g1, W2, b, t, sh, gf, sx);
    if (t < DBLK) out_final[b * DBLK + t] = sx[t];
    if (t == 0) ld_final[b] = ld + ld0[b];
}

extern "C" void kernel_launch(void* const* d_in, const int* in_sizes, int n_in,
                              void* d_out, int out_size, void* d_ws, size_t ws_size,
                              hipStream_t stream) {
    const float* inp   = (const float*)d_in[0];
    const float* W0[2] = {(const float*)d_in[1], (const float*)d_in[6]};
    const float* W1[2] = {(const float*)d_in[2], (const float*)d_in[7]};
    const float* W2[2] = {(const float*)d_in[3], (const float*)d_in[8]};
    const float* b0[2] = {(const float*)d_in[4], (const float*)d_in[9]};
    const float* b1[2] = {(const float*)d_in[5], (const float*)d_in[10]};

    char* w = (char*)d_ws;
    size_t off = 0;
    unsigned short* W1bf = (unsigned short*)(w + off); off += (size_t)2 * NN * NN * 2; // 16 MB
    unsigned short* h0b  = (unsigned short*)(w + off); off += (size_t)BATCH * NN * 2;
    unsigned short* e0b  = (unsigned short*)(w + off); off += (size_t)BATCH * NN * 2;
    float* mmax = (float*)(w + off); off += (size_t)BATCH * DBLK * 4;
    unsigned short* h1 = (unsigned short*)(w + off); off += (size_t)BATCH * NN * 2;
    float* g1   = (float*)(w + off); off += (size_t)BATCH * NN * 4;
    float* ld0  = (float*)(w + off); off += (size_t)BATCH * 4;

    float* out_final = (float*)d_out;                 // (256,16)
    float* ld_final  = (float*)d_out + BATCH * DBLK;  // (256,)

    // P1: convert flow0 W1 (pipelined pairs) + layer0 flow 0
    k_prep<<<dim3(1024 + BATCH), dim3(256), 0, stream>>>(
        W1[0], W1bf, inp, W0[0], b0[0], h0b, e0b, mmax);

    // P2: layer1 flow 0  ∥  convert flow1 W1 (z==4 blocks)
    k_l1<true><<<dim3(DBLK, 16, 5), dim3(512), 0, stream>>>(
        h0b, W1bf, b1[0], e0b, mmax, h1, g1,
        W1[1], W1bf + (size_t)NN * NN);

    // P3: final flow 0 + layer0 flow 1
    k_fin0<<<dim3(BATCH), dim3(512), 0, stream>>>(
        h1, g1, W2[0], W0[1], b0[1], h0b, e0b, mmax, ld0);

    // P4: layer1 flow 1
    k_l1<false><<<dim3(DBLK, 16, 4), dim3(512), 0, stream>>>(
        h0b, W1bf + (size_t)NN * NN, b1[1], e0b, mmax, h1, g1,
        nullptr, nullptr);

    // P5: final flow 1
    k_fin1<<<dim3(BATCH), dim3(512), 0, stream>>>(
        h1, g1, W2[1], ld0, out_final, ld_final);
}